// Round 1
// baseline (652.452 us; speedup 1.0000x reference)
//
#include <hip/hip_runtime.h>

#define NB 64
#define NS 2048
#define ND 512

typedef short s16x8 __attribute__((ext_vector_type(8)));
typedef float f32x16 __attribute__((ext_vector_type(16)));

__device__ __forceinline__ unsigned short bf16_rnd(float x){
  union { float f; unsigned u; } c; c.f = x;
  unsigned r = c.u + 0x7FFFu + ((c.u >> 16) & 1u);
  return (unsigned short)(r >> 16);
}
__device__ __forceinline__ float bf16f(unsigned short h){
  union { unsigned u; float f; } c; c.u = ((unsigned)h) << 16;
  return c.f;
}
__device__ __forceinline__ float fast_tanh(float x){
  float e = __expf(2.0f * x);
  return 1.0f - 2.0f / (e + 1.0f);
}

// ---------------------------------------------------------------------------
// K1a: Wc [512x512] f32 -> bf16 hi/lo fragments, layout [ks 32][n 16][var 2][lane 64][j 8]
// B-frag mapping: col e = n*32 + (lane&31), k = ks*16 + (lane>>5)*8 + j
// ---------------------------------------------------------------------------
__global__ void k_prep_wc(const float* __restrict__ Wc, unsigned short* __restrict__ wcf){
  int t  = blockIdx.x * 256 + threadIdx.x;   // 32768 threads total
  int l  = t & 63;
  int n  = (t >> 6) & 15;
  int ks = t >> 10;
  int e  = n * 32 + (l & 31);
  int d0 = ks * 16 + ((l >> 5) * 8);
  const float4* g4 = (const float4*)(Wc + (size_t)e * ND + d0);
  float4 x0 = g4[0], x1 = g4[1];
  float xs[8] = {x0.x,x0.y,x0.z,x0.w,x1.x,x1.y,x1.z,x1.w};
  s16x8 hv, lv;
#pragma unroll
  for(int j=0;j<8;j++){
    float x = xs[j];
    unsigned short h = bf16_rnd(x);
    hv[j] = (short)h;
    lv[j] = (short)bf16_rnd(x - bf16f(h));
  }
  size_t base = ((size_t)(ks*16 + n))*1024 + (size_t)l*8;   // shorts
  *(s16x8*)(wcf + base)       = hv;   // var 0 (hi)
  *(s16x8*)(wcf + base + 512) = lv;   // var 1 (lo)
}

// ---------------------------------------------------------------------------
// K1b: wq[b,e] = dot(source[b,:], Wq[e,:]) + bq[e]   (fp32 exact, tiny)
// ---------------------------------------------------------------------------
__global__ void k_wq(const float* __restrict__ src, const float* __restrict__ Wq,
                     const float* __restrict__ bq, float* __restrict__ wq){
  __shared__ float s_src[ND];
  int b = blockIdx.x;
  for(int i=threadIdx.x;i<ND;i+=256) s_src[i] = src[(size_t)b*ND + i];
  __syncthreads();
  for(int e=threadIdx.x; e<ND; e+=256){
    const float4* wr = (const float4*)(Wq + (size_t)e*ND);
    float acc = 0.f;
#pragma unroll 4
    for(int i=0;i<ND/4;i++){
      float4 w4 = wr[i];
      acc += w4.x*s_src[4*i] + w4.y*s_src[4*i+1] + w4.z*s_src[4*i+2] + w4.w*s_src[4*i+3];
    }
    wq[(size_t)b*ND + e] = acc + bq[e];
  }
}

// ---------------------------------------------------------------------------
// K2: scores[b,s] = sum_e v[e] * tanh(wq[b,e] + sum_d mb[b,s,d]*Wc[e,d])
// Block: (b, 64-row s-chunk). 8 waves. mb hi/lo fragments LDS-resident (full K).
// bf16x3: hi*hi + hi*lo + lo*hi via v_mfma_f32_32x32x16_bf16.
// ---------------------------------------------------------------------------
__launch_bounds__(512, 2)
__global__ void k_scores(const float* __restrict__ mb, const unsigned short* __restrict__ wcf,
                         const float* __restrict__ wq, const float* __restrict__ v,
                         float* __restrict__ scores){
  // A-frags: [mt 2][ks 32][var 2][lane 64][j 8] shorts = 128 KB
  __shared__ unsigned short a_lds[2*32*2*64*8];
  __shared__ float wq_s[ND];
  __shared__ float v_s[ND];
  __shared__ float sred[8][64];

  int b  = blockIdx.x >> 5;
  int sc = blockIdx.x & 31;
  int s0 = sc * 64;
  int tid = threadIdx.x;
  int w = tid >> 6;        // wave 0..7
  int l = tid & 63;        // lane

  if(tid < ND){ wq_s[tid] = wq[(size_t)b*ND + tid]; v_s[tid] = v[tid]; }

  // --- stage mb rows [s0, s0+64) as hi/lo fragments ---
  const float* mbb = mb + ((size_t)b*NS + s0) * ND;
#pragma unroll
  for(int i=0;i<8;i++){
    int flat = w + 8*i;            // 0..63 -> (mt, ks)
    int mt = flat >> 5;
    int ks = flat & 31;
    int r  = mt*32 + (l & 31);
    int k0 = ks*16 + ((l >> 5) * 8);
    const float4* g4 = (const float4*)(mbb + (size_t)r*ND + k0);
    float4 x0 = g4[0], x1 = g4[1];
    float xs[8] = {x0.x,x0.y,x0.z,x0.w,x1.x,x1.y,x1.z,x1.w};
    s16x8 hv, lv;
#pragma unroll
    for(int j=0;j<8;j++){
      float x = xs[j];
      unsigned short h = bf16_rnd(x);
      hv[j] = (short)h;
      lv[j] = (short)bf16_rnd(x - bf16f(h));
    }
    int base = (((mt*32 + ks)*2)*64 + l) * 8;   // shorts
    *(s16x8*)(a_lds + base)       = hv;
    *(s16x8*)(a_lds + base + 512) = lv;
  }
  __syncthreads();

  const s16x8* aptr = (const s16x8*)a_lds;
  const s16x8* bptr = (const s16x8*)wcf;

  f32x16 acc[2][2];
#pragma unroll
  for(int mt=0;mt<2;mt++)
#pragma unroll
    for(int nt=0;nt<2;nt++)
#pragma unroll
      for(int q=0;q<16;q++) acc[mt][nt][q] = 0.f;

  int n0 = w * 2;
#pragma unroll 2
  for(int ks=0;ks<32;ks++){
    s16x8 a0h = aptr[       ks*128      + l];
    s16x8 a0l = aptr[       ks*128 + 64 + l];
    s16x8 a1h = aptr[4096 + ks*128      + l];
    s16x8 a1l = aptr[4096 + ks*128 + 64 + l];
    const s16x8* bp = bptr + ((size_t)ks*16 + n0)*128 + l;
    s16x8 b0h = bp[0];
    s16x8 b0l = bp[64];
    s16x8 b1h = bp[128];
    s16x8 b1l = bp[192];

    acc[0][0] = __builtin_amdgcn_mfma_f32_32x32x16_bf16(a0h, b0h, acc[0][0], 0,0,0);
    acc[1][0] = __builtin_amdgcn_mfma_f32_32x32x16_bf16(a1h, b0h, acc[1][0], 0,0,0);
    acc[0][1] = __builtin_amdgcn_mfma_f32_32x32x16_bf16(a0h, b1h, acc[0][1], 0,0,0);
    acc[1][1] = __builtin_amdgcn_mfma_f32_32x32x16_bf16(a1h, b1h, acc[1][1], 0,0,0);
    acc[0][0] = __builtin_amdgcn_mfma_f32_32x32x16_bf16(a0h, b0l, acc[0][0], 0,0,0);
    acc[1][0] = __builtin_amdgcn_mfma_f32_32x32x16_bf16(a1h, b0l, acc[1][0], 0,0,0);
    acc[0][1] = __builtin_amdgcn_mfma_f32_32x32x16_bf16(a0h, b1l, acc[0][1], 0,0,0);
    acc[1][1] = __builtin_amdgcn_mfma_f32_32x32x16_bf16(a1h, b1l, acc[1][1], 0,0,0);
    acc[0][0] = __builtin_amdgcn_mfma_f32_32x32x16_bf16(a0l, b0h, acc[0][0], 0,0,0);
    acc[1][0] = __builtin_amdgcn_mfma_f32_32x32x16_bf16(a1l, b0h, acc[1][0], 0,0,0);
    acc[0][1] = __builtin_amdgcn_mfma_f32_32x32x16_bf16(a0l, b1h, acc[0][1], 0,0,0);
    acc[1][1] = __builtin_amdgcn_mfma_f32_32x32x16_bf16(a1l, b1h, acc[1][1], 0,0,0);
  }

  // --- epilogue: scores partials.  C/D: col e = n*32+(l&31), row = (r&3)+8*(r>>2)+4*(l>>5)
  float sp[2][16];
#pragma unroll
  for(int mt=0;mt<2;mt++)
#pragma unroll
    for(int r=0;r<16;r++) sp[mt][r] = 0.f;

#pragma unroll
  for(int nt=0;nt<2;nt++){
    int e = (n0 + nt)*32 + (l & 31);
    float wqe = wq_s[e];
    float ve  = v_s[e];
#pragma unroll
    for(int mt=0;mt<2;mt++)
#pragma unroll
      for(int r=0;r<16;r++){
        float th = fast_tanh(acc[mt][nt][r] + wqe);
        sp[mt][r] += ve * th;
      }
  }

  // reduce over the 32 e-lanes (stays within each 32-lane half)
#pragma unroll
  for(int o=1;o<32;o<<=1){
#pragma unroll
    for(int mt=0;mt<2;mt++)
#pragma unroll
      for(int r=0;r<16;r++)
        sp[mt][r] += __shfl_xor(sp[mt][r], o, 64);
  }

  if((l & 31) == 0){
    int half = l >> 5;
#pragma unroll
    for(int mt=0;mt<2;mt++)
#pragma unroll
      for(int r=0;r<16;r++){
        int row = mt*32 + (r&3) + 8*(r>>2) + 4*half;
        sred[w][row] = sp[mt][r];
      }
  }
  __syncthreads();
  if(tid < 64){
    float s = 0.f;
#pragma unroll
    for(int ww=0;ww<8;ww++) s += sred[ww][tid];
    scores[(size_t)b*NS + s0 + tid] = s;
  }
}

// ---------------------------------------------------------------------------
// K3: masked softmax over S per batch row.  Handles int32 or int64 lengths.
// ---------------------------------------------------------------------------
__global__ void k_softmax(const float* __restrict__ scores, const unsigned* __restrict__ lraw,
                          float* __restrict__ align){
  __shared__ float red[4];
  int b = blockIdx.x, tid = threadIdx.x;
  bool is64 = (lraw[1] == 0u);          // int64: high word of len[0] is 0; int32: len[1] >= 1
  int len = (int)(is64 ? lraw[2*b] : lraw[b]);

  float loc[8];
  float mx = -1e30f;
#pragma unroll
  for(int i=0;i<8;i++){
    int s = tid + i*256;
    float val = scores[(size_t)b*NS + s];
    loc[i] = (s < len) ? val : -1e30f;
    mx = fmaxf(mx, loc[i]);
  }
#pragma unroll
  for(int o=1;o<64;o<<=1) mx = fmaxf(mx, __shfl_xor(mx, o, 64));
  if((tid & 63) == 0) red[tid >> 6] = mx;
  __syncthreads();
  mx = fmaxf(fmaxf(red[0],red[1]), fmaxf(red[2],red[3]));
  __syncthreads();

  float sum = 0.f;
#pragma unroll
  for(int i=0;i<8;i++){
    int s = tid + i*256;
    loc[i] = (s < len) ? __expf(loc[i] - mx) : 0.f;
    sum += loc[i];
  }
#pragma unroll
  for(int o=1;o<64;o<<=1) sum += __shfl_xor(sum, o, 64);
  if((tid & 63) == 0) red[tid >> 6] = sum;
  __syncthreads();
  sum = red[0] + red[1] + red[2] + red[3];
  float inv = 1.f / sum;
#pragma unroll
  for(int i=0;i<8;i++){
    int s = tid + i*256;
    align[(size_t)b*NS + s] = loc[i] * inv;
  }
}

// ---------------------------------------------------------------------------
// K4: c[b,d] = sum_s align[b,s] * mb[b,s,d]   (partial chunks + atomics)
// ---------------------------------------------------------------------------
__global__ void k_context(const float* __restrict__ mb, const float* __restrict__ align,
                          float* __restrict__ c){
  int b  = blockIdx.x >> 4;
  int sc = blockIdx.x & 15;
  int s0 = sc * 128;
  int d0 = threadIdx.x * 2;
  const float* base = mb + ((size_t)b*NS + s0)*ND + d0;
  float a0 = 0.f, a1 = 0.f;
  for(int i=0;i<128;i++){
    float al = align[(size_t)b*NS + s0 + i];
    if(al != 0.f){
      float2 m = *(const float2*)(base + (size_t)i*ND);
      a0 += al * m.x;
      a1 += al * m.y;
    }
  }
  atomicAdd(&c[(size_t)b*ND + d0],     a0);
  atomicAdd(&c[(size_t)b*ND + d0 + 1], a1);
}

// ---------------------------------------------------------------------------
extern "C" void kernel_launch(void* const* d_in, const int* in_sizes, int n_in,
                              void* d_out, int out_size, void* d_ws, size_t ws_size,
                              hipStream_t stream) {
  (void)in_sizes; (void)n_in; (void)out_size; (void)ws_size;
  const float*    src  = (const float*)d_in[0];
  const float*    mb   = (const float*)d_in[1];
  const unsigned* lens = (const unsigned*)d_in[2];
  const float*    Wq   = (const float*)d_in[3];
  const float*    bq   = (const float*)d_in[4];
  const float*    Wc   = (const float*)d_in[5];
  const float*    v    = (const float*)d_in[6];

  float* out   = (float*)d_out;
  float* c     = out;                 // [64, 512]
  float* align = out + NB*ND;         // [64, 2048]

  char* ws = (char*)d_ws;
  unsigned short* wcf    = (unsigned short*)ws;                       // 1 MB
  float*          wq     = (float*)(ws + (1<<20));                    // 128 KB
  float*          scores = (float*)(ws + (1<<20) + (128<<10));        // 512 KB

  hipMemsetAsync(c, 0, NB*ND*sizeof(float), stream);
  k_prep_wc<<<128, 256, 0, stream>>>(Wc, wcf);
  k_wq<<<64, 256, 0, stream>>>(src, Wq, bq, wq);
  k_scores<<<NB*(NS/64), 512, 0, stream>>>(mb, wcf, wq, v, scores);
  k_softmax<<<NB, 256, 0, stream>>>(scores, lens, align);
  k_context<<<NB*16, 256, 0, stream>>>(mb, align, c);
}

// Round 3
// 529.958 us; speedup vs baseline: 1.2311x; 1.2311x over previous
//
#include <hip/hip_runtime.h>

#define NB 64
#define NS 2048
#define ND 512

typedef _Float16 f16x8 __attribute__((ext_vector_type(8)));
typedef float f32x16 __attribute__((ext_vector_type(16)));

__device__ __forceinline__ float fast_tanh(float x){
  float e = __expf(2.0f * x);
  return 1.0f - 2.0f / (e + 1.0f);
}

// ---------------------------------------------------------------------------
// K1a: Wc [512x512] f32 -> fp16 B-fragments, layout [ks 32][n 16][lane 64][j 8]
// B-frag mapping: col e = n*32 + (lane&31), k = ks*16 + (lane>>5)*8 + j
// ---------------------------------------------------------------------------
__global__ void k_prep_wc(const float* __restrict__ Wc, _Float16* __restrict__ wcf){
  int t  = blockIdx.x * 256 + threadIdx.x;   // 32768 threads total
  int l  = t & 63;
  int n  = (t >> 6) & 15;
  int ks = t >> 10;
  int e  = n * 32 + (l & 31);
  int d0 = ks * 16 + ((l >> 5) * 8);
  const float4* g4 = (const float4*)(Wc + (size_t)e * ND + d0);
  float4 x0 = g4[0], x1 = g4[1];
  float xs[8] = {x0.x,x0.y,x0.z,x0.w,x1.x,x1.y,x1.z,x1.w};
  f16x8 hv;
#pragma unroll
  for(int j=0;j<8;j++) hv[j] = (_Float16)xs[j];
  size_t base = ((size_t)((ks*16 + n)*64 + l)) * 8;   // halves
  *(f16x8*)(wcf + base) = hv;
}

// ---------------------------------------------------------------------------
// K1b: wq[b,e] = dot(source[b,:], Wq[e,:]) + bq[e]   (fp32 exact, tiny)
// ---------------------------------------------------------------------------
__global__ void k_wq(const float* __restrict__ src, const float* __restrict__ Wq,
                     const float* __restrict__ bq, float* __restrict__ wq){
  __shared__ float s_src[ND];
  int b = blockIdx.x;
  for(int i=threadIdx.x;i<ND;i+=256) s_src[i] = src[(size_t)b*ND + i];
  __syncthreads();
  for(int e=threadIdx.x; e<ND; e+=256){
    const float4* wr = (const float4*)(Wq + (size_t)e*ND);
    float acc = 0.f;
#pragma unroll 4
    for(int i=0;i<ND/4;i++){
      float4 w4 = wr[i];
      acc += w4.x*s_src[4*i] + w4.y*s_src[4*i+1] + w4.z*s_src[4*i+2] + w4.w*s_src[4*i+3];
    }
    wq[(size_t)b*ND + e] = acc + bq[e];
  }
}

// ---------------------------------------------------------------------------
// K2: scores[b,s] = sum_e v[e] * tanh(wq[b,e] + sum_d mb[b,s,d]*Wc[e,d])
// Block: (b, 64-row s-chunk). 8 waves. fp16 A-fragments LDS-resident (64 KB ->
// 2 blocks/CU). 4 MFMA (32x32x16_f16) per ks step per wave.
// ---------------------------------------------------------------------------
__launch_bounds__(512, 4)
__global__ void k_scores(const float* __restrict__ mb, const _Float16* __restrict__ wcf,
                         const float* __restrict__ wq, const float* __restrict__ v,
                         float* __restrict__ scores){
  // A-frags: [mt 2][ks 32][lane 64][j 8] halves = 64 KB
  __shared__ _Float16 a_lds[2*32*64*8];
  __shared__ float wq_s[ND];
  __shared__ float v_s[ND];
  __shared__ float sred[8][64];

  int b  = blockIdx.x >> 5;
  int sc = blockIdx.x & 31;
  int s0 = sc * 64;
  int tid = threadIdx.x;
  int w = tid >> 6;        // wave 0..7
  int l = tid & 63;        // lane

  if(tid < ND){ wq_s[tid] = wq[(size_t)b*ND + tid]; v_s[tid] = v[tid]; }

  // --- stage mb rows [s0, s0+64) as fp16 fragments ---
  const float* mbb = mb + ((size_t)b*NS + s0) * ND;
#pragma unroll
  for(int i=0;i<8;i++){
    int flat = w + 8*i;            // 0..63 -> (mt, ks)
    int mt = flat >> 5;
    int ks = flat & 31;
    int r  = mt*32 + (l & 31);
    int k0 = ks*16 + ((l >> 5) * 8);
    const float4* g4 = (const float4*)(mbb + (size_t)r*ND + k0);
    float4 x0 = g4[0], x1 = g4[1];
    float xs[8] = {x0.x,x0.y,x0.z,x0.w,x1.x,x1.y,x1.z,x1.w};
    f16x8 hv;
#pragma unroll
    for(int j=0;j<8;j++) hv[j] = (_Float16)xs[j];
    int base = ((mt*32 + ks)*64 + l) * 8;   // halves
    *(f16x8*)(a_lds + base) = hv;
  }
  __syncthreads();

  const f16x8* aptr = (const f16x8*)a_lds;
  const f16x8* bptr = (const f16x8*)wcf;

  f32x16 acc[2][2];
#pragma unroll
  for(int mt=0;mt<2;mt++)
#pragma unroll
    for(int nt=0;nt<2;nt++)
#pragma unroll
      for(int q=0;q<16;q++) acc[mt][nt][q] = 0.f;

  int n0 = w * 2;
#pragma unroll 4
  for(int ks=0;ks<32;ks++){
    f16x8 a0 = aptr[       ks*64 + l];
    f16x8 a1 = aptr[2048 + ks*64 + l];
    const f16x8* bp = bptr + ((size_t)ks*16 + n0)*64 + l;
    f16x8 b0 = bp[0];
    f16x8 b1 = bp[64];

    acc[0][0] = __builtin_amdgcn_mfma_f32_32x32x16_f16(a0, b0, acc[0][0], 0,0,0);
    acc[1][0] = __builtin_amdgcn_mfma_f32_32x32x16_f16(a1, b0, acc[1][0], 0,0,0);
    acc[0][1] = __builtin_amdgcn_mfma_f32_32x32x16_f16(a0, b1, acc[0][1], 0,0,0);
    acc[1][1] = __builtin_amdgcn_mfma_f32_32x32x16_f16(a1, b1, acc[1][1], 0,0,0);
  }

  // --- epilogue: scores partials.  C/D: col e = n*32+(l&31), row = (r&3)+8*(r>>2)+4*(l>>5)
  float sp[2][16];
#pragma unroll
  for(int mt=0;mt<2;mt++)
#pragma unroll
    for(int r=0;r<16;r++) sp[mt][r] = 0.f;

#pragma unroll
  for(int nt=0;nt<2;nt++){
    int e = (n0 + nt)*32 + (l & 31);
    float wqe = wq_s[e];
    float ve  = v_s[e];
#pragma unroll
    for(int mt=0;mt<2;mt++)
#pragma unroll
      for(int r=0;r<16;r++){
        float th = fast_tanh(acc[mt][nt][r] + wqe);
        sp[mt][r] += ve * th;
      }
  }

  // reduce over the 32 e-lanes (stays within each 32-lane half)
#pragma unroll
  for(int o=1;o<32;o<<=1){
#pragma unroll
    for(int mt=0;mt<2;mt++)
#pragma unroll
      for(int r=0;r<16;r++)
        sp[mt][r] += __shfl_xor(sp[mt][r], o, 64);
  }

  if((l & 31) == 0){
    int half = l >> 5;
#pragma unroll
    for(int mt=0;mt<2;mt++)
#pragma unroll
      for(int r=0;r<16;r++){
        int row = mt*32 + (r&3) + 8*(r>>2) + 4*half;
        sred[w][row] = sp[mt][r];
      }
  }
  __syncthreads();
  if(tid < 64){
    float s = 0.f;
#pragma unroll
    for(int ww=0;ww<8;ww++) s += sred[ww][tid];
    scores[(size_t)b*NS + s0 + tid] = s;
  }
}

// ---------------------------------------------------------------------------
// K3: masked softmax over S per batch row.  Handles int32 or int64 lengths.
// ---------------------------------------------------------------------------
__global__ void k_softmax(const float* __restrict__ scores, const unsigned* __restrict__ lraw,
                          float* __restrict__ align){
  __shared__ float red[4];
  int b = blockIdx.x, tid = threadIdx.x;
  bool is64 = (lraw[1] == 0u);          // int64: high word of len[0] is 0; int32: len[1] >= 1
  int len = (int)(is64 ? lraw[2*b] : lraw[b]);

  float loc[8];
  float mx = -1e30f;
#pragma unroll
  for(int i=0;i<8;i++){
    int s = tid + i*256;
    float val = scores[(size_t)b*NS + s];
    loc[i] = (s < len) ? val : -1e30f;
    mx = fmaxf(mx, loc[i]);
  }
#pragma unroll
  for(int o=1;o<64;o<<=1) mx = fmaxf(mx, __shfl_xor(mx, o, 64));
  if((tid & 63) == 0) red[tid >> 6] = mx;
  __syncthreads();
  mx = fmaxf(fmaxf(red[0],red[1]), fmaxf(red[2],red[3]));
  __syncthreads();

  float sum = 0.f;
#pragma unroll
  for(int i=0;i<8;i++){
    int s = tid + i*256;
    loc[i] = (s < len) ? __expf(loc[i] - mx) : 0.f;
    sum += loc[i];
  }
#pragma unroll
  for(int o=1;o<64;o<<=1) sum += __shfl_xor(sum, o, 64);
  if((tid & 63) == 0) red[tid >> 6] = sum;
  __syncthreads();
  sum = red[0] + red[1] + red[2] + red[3];
  float inv = 1.f / sum;
#pragma unroll
  for(int i=0;i<8;i++){
    int s = tid + i*256;
    align[(size_t)b*NS + s] = loc[i] * inv;
  }
}

// ---------------------------------------------------------------------------
// K4: c[b,d] = sum_s align[b,s] * mb[b,s,d].  Unconditional FMA, align in LDS,
// 1024 blocks x 512 threads (one d-column per thread), full occupancy.
// NOTE: launch MUST use 512 threads — each thread covers exactly one of ND=512
// columns (R1 failed because this was launched with 256 threads).
// ---------------------------------------------------------------------------
__global__ void k_context(const float* __restrict__ mb, const float* __restrict__ align,
                          float* __restrict__ c){
  __shared__ float als[128];
  int b  = blockIdx.x >> 4;
  int sc = blockIdx.x & 15;
  int s0 = sc * 128;
  int tid = threadIdx.x;
  if(tid < 128) als[tid] = align[(size_t)b*NS + s0 + tid];
  __syncthreads();
  const float* base = mb + ((size_t)b*NS + s0)*ND + tid;
  float a = 0.f;
#pragma unroll 8
  for(int i=0;i<128;i++){
    a += als[i] * base[(size_t)i*ND];
  }
  atomicAdd(&c[(size_t)b*ND + tid], a);
}

// ---------------------------------------------------------------------------
extern "C" void kernel_launch(void* const* d_in, const int* in_sizes, int n_in,
                              void* d_out, int out_size, void* d_ws, size_t ws_size,
                              hipStream_t stream) {
  (void)in_sizes; (void)n_in; (void)out_size; (void)ws_size;
  const float*    src  = (const float*)d_in[0];
  const float*    mb   = (const float*)d_in[1];
  const unsigned* lens = (const unsigned*)d_in[2];
  const float*    Wq   = (const float*)d_in[3];
  const float*    bq   = (const float*)d_in[4];
  const float*    Wc   = (const float*)d_in[5];
  const float*    v    = (const float*)d_in[6];

  float* out   = (float*)d_out;
  float* c     = out;                 // [64, 512]
  float* align = out + NB*ND;         // [64, 2048]

  char* ws = (char*)d_ws;
  _Float16* wcf    = (_Float16*)ws;                                  // 512 KB
  float*    wq     = (float*)(ws + (512<<10));                       // 128 KB
  float*    scores = (float*)(ws + (512<<10) + (128<<10));           // 512 KB

  hipMemsetAsync(c, 0, NB*ND*sizeof(float), stream);
  k_prep_wc<<<128, 256, 0, stream>>>(Wc, wcf);
  k_wq<<<64, 256, 0, stream>>>(src, Wq, bq, wq);
  k_scores<<<NB*(NS/64), 512, 0, stream>>>(mb, wcf, wq, v, scores);
  k_softmax<<<NB, 256, 0, stream>>>(scores, lens, align);
  k_context<<<NB*16, 512, 0, stream>>>(mb, align, c);
}